// Round 9
// baseline (113.633 us; speedup 1.0000x reference)
//
#include <hip/hip_runtime.h>
#include <hip/hip_bf16.h>
#include <math.h>

// OLCNN: x(B,1,9,9) -> conv3x3(16ch) -> sigmoid -> maxpool2x2 floor (7x7->3x3)
//        -> conv2 (144->32) via MFMA -> sigmoid -> fc 32->4.  B = 131072 fp32.
// One thread = one sample; 512 blocks x 256 = 2 waves/SIMD (grid-pinned).
//
// Round 9 — kill the three serial-latency chains R8 left (main kernel is
// ~9us of issue + ~30us of stalls at 2 waves/SIMD):
//  1. A-fragments built by ds_bpermute half-swap (shfl_xor 32) from the
//     producer lanes' registers — replaces the per-band LDS write->read
//     round trip (72 writes + 36 b64 reads + forced lgkm serialization).
//     Index algebra: lane l's A0 row is sample l&31, A1 row is (l&31)+32;
//     s_i = h0?own_hi:own_lo, t=shfl_xor(s,32), A0=h0?own_lo:t, A1=h0?t:own_hi.
//     Same assumed k-map as the prep B layout => R8's cancellation argument
//     still holds (R8 passed, absmax 0.0078).
//  2. x software pipeline: band pi+1's loads issue at the top of band pi's
//     body (sched_barrier pins them above the math) -> vmcnt wait lands
//     after ~3k cyc of conv1 instead of before it.
//  3. 9 loop-invariant B-fragment dwordx4 loads hoisted above the band loop.
// LDS is now epilogue-only. conv1 stays R5-proven packed fp32.

typedef float v2f __attribute__((ext_vector_type(2)));
typedef float f4  __attribute__((ext_vector_type(4)));
typedef f4 uf4 __attribute__((aligned(4)));   // align-4 dwordx4 (x rows 4B-aligned)
typedef __bf16 bf16x2 __attribute__((ext_vector_type(2)));
typedef __bf16 bf16x8 __attribute__((ext_vector_type(8)));
typedef float f32x16 __attribute__((ext_vector_type(16)));
typedef unsigned int u32;
typedef u32 u32x4 __attribute__((ext_vector_type(4)));

#define BLOCK 256
#define LOG2E 1.4426950408889634f

// ws layout:
//   bytes  [0 .. 9216): w2 B-frags bf16 [pi][kb][lane][j]  (3*3*64*8 u16)
//   floats [2304 .. 2624): small block staged to LDS:
#define OFF_SMALL 2304
#define S_W1P  0      // [8][9][2]  w1 * log2e, ch-paired
#define S_B1P  144    // [8][2]     b1 * log2e, ch-paired
#define S_FCWP 160    // [4][16][2] fc_w ch-paired
#define S_B2S  288    // [32]       b2 * log2e
#define SMALL_FLOATS 320
#define PREP_ITEMS (4608 + SMALL_FLOATS)

__device__ __forceinline__ float sig2(float s) {
    // arg pre-scaled by log2e: sigmoid = 1/(1+2^-s)
    return __builtin_amdgcn_rcpf(1.0f + __builtin_amdgcn_exp2f(-s));
}

__device__ __forceinline__ u32 pack_bf(float a, float b) {
    bf16x2 p; p.x = (__bf16)a; p.y = (__bf16)b;
    return __builtin_bit_cast(u32, p);
}

__global__ void prep_kernel(const float* __restrict__ w1,
                            const float* __restrict__ b1,
                            const float* __restrict__ w2,
                            const float* __restrict__ b2,
                            const float* __restrict__ fcw,
                            float* __restrict__ ws) {
    int i = blockIdx.x * blockDim.x + threadIdx.x;
    if (i < 4608) {
        // B-frag: value at (pi, kb, lane, j) = w2[oc = lane&31][d] * log2e,
        // band-feature k = kb*16 + (lane>>5)*8 + j, d = (k/3)*9 + pi*3 + k%3
        int j = i & 7, lane = (i >> 3) & 63, kb = (i >> 9) % 3, pi = i / 1536;
        int k = kb * 16 + (lane >> 5) * 8 + j;
        int o = k / 3, pj = k - 3 * o;
        float v = w2[(lane & 31) * 144 + o * 9 + pi * 3 + pj] * LOG2E;
        ((__bf16*)ws)[i] = (__bf16)v;            // RNE convert
    } else if (i < PREP_ITEMS) {
        int r = i - 4608;
        float v;
        if (r < S_B1P) {                         // w1 ch-paired: [op][k][h]
            int h = r & 1, k = (r >> 1) % 9, op = (r >> 1) / 9;
            v = w1[(2 * op + h) * 9 + k] * LOG2E;
        } else if (r < S_FCWP) {                 // b1 ch-paired: [op][h]
            int q = r - S_B1P;
            v = b1[2 * (q >> 1) + (q & 1)] * LOG2E;
        } else if (r < S_B2S) {                  // fcw ch-paired: [row][j][h]
            int q = r - S_FCWP;
            int h = q & 1, j = (q >> 1) % 16, rr = (q >> 1) / 16;
            v = fcw[rr * 32 + 2 * j + h];
        } else {                                 // b2 * log2e
            v = b2[r - S_B2S] * LOG2E;
        }
        ws[OFF_SMALL + r] = v;
    }
}

#define LOADB(dst, pi_)                                              \
    do {                                                             \
        _Pragma("unroll")                                            \
        for (int r_ = 0; r_ < 4; ++r_) {                             \
            const float* rp_ = xs + (2 * (pi_) + r_) * 9;            \
            f4 a_ = *(const uf4*)rp_;                                \
            f4 b_ = *(const uf4*)(rp_ + 4);                          \
            dst[r_][0] = a_.x; dst[r_][1] = a_.y;                    \
            dst[r_][2] = a_.z; dst[r_][3] = a_.w;                    \
            dst[r_][4] = b_.x; dst[r_][5] = b_.y;                    \
            dst[r_][6] = b_.z; dst[r_][7] = b_.w;                    \
        }                                                            \
    } while (0)

__global__ __launch_bounds__(BLOCK, 2) void olcnn_kernel(
    const float* __restrict__ xg,   // (B,81)
    const float* __restrict__ wsf,  // prep output
    const float* __restrict__ fcb,  // (4,)
    float* __restrict__ out)        // (B,4)
{
    // epilogue-only scratch: h2 transpose, 64 x 34 dw per wave
    __shared__ u32 lds_scr[4 * 2176];
    __shared__ __align__(16) float lws[SMALL_FLOATS];

    const int tid  = threadIdx.x;
    const int lane = tid & 63;
    const int wid  = tid >> 6;
    u32* scr = lds_scr + wid * 2176;

    if (tid < SMALL_FLOATS / 4)
        ((f4*)lws)[tid] = ((const f4*)(wsf + OFF_SMALL))[tid];
    __syncthreads();

    const v2f* w1p  = (const v2f*)(lws + S_W1P);
    const v2f* b1p  = (const v2f*)(lws + S_B1P);
    const v2f* fcwp = (const v2f*)(lws + S_FCWP);

    const int t = blockIdx.x * BLOCK + tid;
    const float* xs = xg + (long long)t * 81;

    // hoisted loop-invariant B-fragments (9 x dwordx4 = 36 VGPR, L2-hit)
    const u32x4* bfrag_g = (const u32x4*)wsf;
    u32x4 bfr[9];
    #pragma unroll
    for (int q = 0; q < 9; ++q) bfr[q] = bfrag_g[q * 64 + lane];

    f32x16 acc0{};                  // M-tile 0: samples 0..31 (wave-local)
    f32x16 acc1{};                  // M-tile 1: samples 32..63

    const bool h0 = (lane < 32);

    float xb[4][8], xbn[4][8];
    LOADB(xbn, 0);                  // prime the pipeline

    #pragma unroll 1                // rolled: body fits I$
    for (int pi = 0; pi < 3; ++pi) {
        // ---- consume prefetched band (vmcnt wait lands here) ----
        #pragma unroll
        for (int r = 0; r < 4; ++r)
            #pragma unroll
            for (int c = 0; c < 8; ++c) {
                float v = xbn[r][c];
                asm volatile("" : "+v"(v));      // pin: distinct reg, no remat
                xb[r][c] = v;
            }
        // ---- issue next band's loads now; keep them above the math ----
        if (pi < 2) LOADB(xbn, pi + 1);
        __builtin_amdgcn_sched_barrier(0);

        // ---- conv1 + pool + sigmoid -> packed bf16 pairs pk[24] ----
        u32 pk[24];
        #pragma unroll
        for (int op = 0; op < 8; ++op) {        // channel pair (2op, 2op+1)
            v2f wv[9];
            #pragma unroll
            for (int k = 0; k < 9; ++k) wv[k] = w1p[op * 9 + k];
            const v2f bb = b1p[op];
            v2f vm[3];
            #pragma unroll
            for (int pj = 0; pj < 3; ++pj) {
                v2f vmax;
                #pragma unroll
                for (int dh = 0; dh < 2; ++dh)
                    #pragma unroll
                    for (int dw = 0; dw < 2; ++dw) {
                        v2f s = bb;
                        #pragma unroll
                        for (int i = 0; i < 3; ++i)
                            #pragma unroll
                            for (int jj = 0; jj < 3; ++jj) {
                                float xv = xb[dh + i][2 * pj + dw + jj];
                                s = __builtin_elementwise_fma(
                                        (v2f){xv, xv}, wv[i * 3 + jj], s);
                            }
                        if (dh == 0 && dw == 0) vmax = s;
                        else vmax = __builtin_elementwise_max(vmax, s);
                    }
                vm[pj] = vmax;
            }
            // features f = ch*3+pj, ch = 2op / 2op+1 -> dwords 3op..3op+2
            float s00 = sig2(vm[0].x), s01 = sig2(vm[1].x), s02 = sig2(vm[2].x);
            float s10 = sig2(vm[0].y), s11 = sig2(vm[1].y), s12 = sig2(vm[2].y);
            pk[3 * op + 0] = pack_bf(s00, s01);
            pk[3 * op + 1] = pack_bf(s02, s10);
            pk[3 * op + 2] = pack_bf(s11, s12);
        }

        // ---- A-fragments via half-swap shuffles, then 3 kb of MFMA ----
        #pragma unroll
        for (int kb = 0; kb < 3; ++kb) {
            u32 a0d[4], a1d[4];
            #pragma unroll
            for (int i = 0; i < 4; ++i) {
                u32 lo = pk[kb * 8 + i];         // k = kb*16 + 2i, 2i+1
                u32 hi = pk[kb * 8 + 4 + i];     // k = kb*16 + 8 + 2i, ...
                u32 s  = h0 ? hi : lo;           // what the other half wants
                u32 tt = (u32)__shfl_xor((int)s, 32);
                a0d[i] = h0 ? lo : tt;           // row = lane&31
                a1d[i] = h0 ? tt : hi;           // row = (lane&31)+32
            }
            u32x4 aw0; aw0.x = a0d[0]; aw0.y = a0d[1]; aw0.z = a0d[2]; aw0.w = a0d[3];
            u32x4 aw1; aw1.x = a1d[0]; aw1.y = a1d[1]; aw1.z = a1d[2]; aw1.w = a1d[3];
            bf16x8 bf = __builtin_bit_cast(bf16x8, bfr[pi * 3 + kb]);
            acc0 = __builtin_amdgcn_mfma_f32_32x32x16_bf16(
                       __builtin_bit_cast(bf16x8, aw0), bf, acc0, 0, 0, 0);
            acc1 = __builtin_amdgcn_mfma_f32_32x32x16_bf16(
                       __builtin_bit_cast(bf16x8, aw1), bf, acc1, 0, 0, 0);
        }
    }

    // ---- bias + sigmoid on C-layout regs, transpose via LDS ----
    // C/D: col(oc) = lane&31, row = (reg&3) + 8*(reg>>2) + 4*(lane>>5)
    const float b2v = lws[S_B2S + (lane & 31)];
    #pragma unroll
    for (int r = 0; r < 16; ++r) {
        const int srow = (r & 3) + 8 * (r >> 2) + 4 * (lane >> 5);
        scr[srow * 34 + (lane & 31)] =
            __builtin_bit_cast(u32, sig2(acc0[r] + b2v));
        scr[(srow + 32) * 34 + (lane & 31)] =
            __builtin_bit_cast(u32, sig2(acc1[r] + b2v));
    }

    // ---- per-thread fc 32->4 (packed), coalesced float4 store ----
    v2f h2[16];
    #pragma unroll
    for (int j = 0; j < 16; ++j)
        h2[j] = *(const v2f*)((const float*)scr + lane * 34 + 2 * j);

    v2f a0 = h2[0] * fcwp[0],  a1 = h2[0] * fcwp[16],
        a2 = h2[0] * fcwp[32], a3 = h2[0] * fcwp[48];
    #pragma unroll
    for (int j = 1; j < 16; ++j) {
        a0 = __builtin_elementwise_fma(h2[j], fcwp[0 * 16 + j], a0);
        a1 = __builtin_elementwise_fma(h2[j], fcwp[1 * 16 + j], a1);
        a2 = __builtin_elementwise_fma(h2[j], fcwp[2 * 16 + j], a2);
        a3 = __builtin_elementwise_fma(h2[j], fcwp[3 * 16 + j], a3);
    }
    ((float4*)out)[t] = make_float4(fcb[0] + a0.x + a0.y,
                                    fcb[1] + a1.x + a1.y,
                                    fcb[2] + a2.x + a2.y,
                                    fcb[3] + a3.x + a3.y);
}

extern "C" void kernel_launch(void* const* d_in, const int* in_sizes, int n_in,
                              void* d_out, int out_size, void* d_ws, size_t ws_size,
                              hipStream_t stream) {
    const float* x   = (const float*)d_in[0];
    const float* w1  = (const float*)d_in[1];
    const float* b1  = (const float*)d_in[2];
    const float* w2  = (const float*)d_in[3];
    const float* b2  = (const float*)d_in[4];
    const float* fcw = (const float*)d_in[5];
    const float* fcb = (const float*)d_in[6];
    float* out = (float*)d_out;
    float* ws  = (float*)d_ws;        // ~10.5 KB used

    prep_kernel<<<dim3((PREP_ITEMS + 255) / 256), dim3(256), 0, stream>>>(
        w1, b1, w2, b2, fcw, ws);

    const int nB = in_sizes[0] / 81;  // 131072, divisible by BLOCK
    olcnn_kernel<<<dim3(nB / BLOCK), dim3(BLOCK), 0, stream>>>(x, ws, fcb, out);
}

// Round 10
// 105.586 us; speedup vs baseline: 1.0762x; 1.0762x over previous
//
#include <hip/hip_runtime.h>
#include <hip/hip_bf16.h>
#include <math.h>

// OLCNN: x(B,1,9,9) -> conv3x3(16ch) -> sigmoid -> maxpool2x2 floor (7x7->3x3)
//        -> conv2 (144->32) via MFMA -> sigmoid -> fc 32->4.  B = 131072 fp32.
// One thread = one sample; 512 blocks x 256 = 2 waves/SIMD (grid-pinned).
//
// Round 10 — kill the R9 scratch spill:
//  * R9 counters: WRITE_SIZE 20 MB (= 36 dw/thread = the hoisted bfr[9]
//    B-fragment array spilled to scratch) + 17 MB extra FETCH (reloads on the
//    MFMA critical path). VGPR=88: __launch_bounds__' min-waves hint never
//    raises the regalloc budget (4 rounds of evidence).
//  * fix 1: amdgpu_waves_per_eu(2,2) pins the occupancy target to what the
//    grid gives anyway -> regalloc budgets ~256 VGPRs, no spill motive.
//  * fix 2: un-hoist bfr -> 3 per-band B-frag loads (12 VGPRs live) issued at
//    the band top, above sched_barrier(0), hidden behind ~3k cyc of conv1.
//  * unchanged (R9-proven): shuffle-built A-fragments (no LDS round trip),
//    x prefetch pipeline, packed-fp32 conv1, MFMA conv2 (absmax 0.0078),
//    epilogue LDS transpose + packed fc.

typedef float v2f __attribute__((ext_vector_type(2)));
typedef float f4  __attribute__((ext_vector_type(4)));
typedef f4 uf4 __attribute__((aligned(4)));   // align-4 dwordx4 (x rows 4B-aligned)
typedef __bf16 bf16x2 __attribute__((ext_vector_type(2)));
typedef __bf16 bf16x8 __attribute__((ext_vector_type(8)));
typedef float f32x16 __attribute__((ext_vector_type(16)));
typedef unsigned int u32;
typedef u32 u32x4 __attribute__((ext_vector_type(4)));

#define BLOCK 256
#define LOG2E 1.4426950408889634f

// ws layout:
//   bytes  [0 .. 9216): w2 B-frags bf16 [pi][kb][lane][j]  (3*3*64*8 u16)
//   floats [2304 .. 2624): small block staged to LDS:
#define OFF_SMALL 2304
#define S_W1P  0      // [8][9][2]  w1 * log2e, ch-paired
#define S_B1P  144    // [8][2]     b1 * log2e, ch-paired
#define S_FCWP 160    // [4][16][2] fc_w ch-paired
#define S_B2S  288    // [32]       b2 * log2e
#define SMALL_FLOATS 320
#define PREP_ITEMS (4608 + SMALL_FLOATS)

__device__ __forceinline__ float sig2(float s) {
    // arg pre-scaled by log2e: sigmoid = 1/(1+2^-s)
    return __builtin_amdgcn_rcpf(1.0f + __builtin_amdgcn_exp2f(-s));
}

__device__ __forceinline__ u32 pack_bf(float a, float b) {
    bf16x2 p; p.x = (__bf16)a; p.y = (__bf16)b;
    return __builtin_bit_cast(u32, p);
}

__global__ void prep_kernel(const float* __restrict__ w1,
                            const float* __restrict__ b1,
                            const float* __restrict__ w2,
                            const float* __restrict__ b2,
                            const float* __restrict__ fcw,
                            float* __restrict__ ws) {
    int i = blockIdx.x * blockDim.x + threadIdx.x;
    if (i < 4608) {
        // B-frag: value at (pi, kb, lane, j) = w2[oc = lane&31][d] * log2e,
        // band-feature k = kb*16 + (lane>>5)*8 + j, d = (k/3)*9 + pi*3 + k%3
        int j = i & 7, lane = (i >> 3) & 63, kb = (i >> 9) % 3, pi = i / 1536;
        int k = kb * 16 + (lane >> 5) * 8 + j;
        int o = k / 3, pj = k - 3 * o;
        float v = w2[(lane & 31) * 144 + o * 9 + pi * 3 + pj] * LOG2E;
        ((__bf16*)ws)[i] = (__bf16)v;            // RNE convert
    } else if (i < PREP_ITEMS) {
        int r = i - 4608;
        float v;
        if (r < S_B1P) {                         // w1 ch-paired: [op][k][h]
            int h = r & 1, k = (r >> 1) % 9, op = (r >> 1) / 9;
            v = w1[(2 * op + h) * 9 + k] * LOG2E;
        } else if (r < S_FCWP) {                 // b1 ch-paired: [op][h]
            int q = r - S_B1P;
            v = b1[2 * (q >> 1) + (q & 1)] * LOG2E;
        } else if (r < S_B2S) {                  // fcw ch-paired: [row][j][h]
            int q = r - S_FCWP;
            int h = q & 1, j = (q >> 1) % 16, rr = (q >> 1) / 16;
            v = fcw[rr * 32 + 2 * j + h];
        } else {                                 // b2 * log2e
            v = b2[r - S_B2S] * LOG2E;
        }
        ws[OFF_SMALL + r] = v;
    }
}

#define LOADB(dst, pi_)                                              \
    do {                                                             \
        _Pragma("unroll")                                            \
        for (int r_ = 0; r_ < 4; ++r_) {                             \
            const float* rp_ = xs + (2 * (pi_) + r_) * 9;            \
            f4 a_ = *(const uf4*)rp_;                                \
            f4 b_ = *(const uf4*)(rp_ + 4);                          \
            dst[r_][0] = a_.x; dst[r_][1] = a_.y;                    \
            dst[r_][2] = a_.z; dst[r_][3] = a_.w;                    \
            dst[r_][4] = b_.x; dst[r_][5] = b_.y;                    \
            dst[r_][6] = b_.z; dst[r_][7] = b_.w;                    \
        }                                                            \
    } while (0)

__global__ __launch_bounds__(BLOCK)
__attribute__((amdgpu_waves_per_eu(2, 2)))
void olcnn_kernel(
    const float* __restrict__ xg,   // (B,81)
    const float* __restrict__ wsf,  // prep output
    const float* __restrict__ fcb,  // (4,)
    float* __restrict__ out)        // (B,4)
{
    // epilogue-only scratch: h2 transpose, 64 x 34 dw per wave
    __shared__ u32 lds_scr[4 * 2176];
    __shared__ __align__(16) float lws[SMALL_FLOATS];

    const int tid  = threadIdx.x;
    const int lane = tid & 63;
    const int wid  = tid >> 6;
    u32* scr = lds_scr + wid * 2176;

    if (tid < SMALL_FLOATS / 4)
        ((f4*)lws)[tid] = ((const f4*)(wsf + OFF_SMALL))[tid];
    __syncthreads();

    const v2f* w1p  = (const v2f*)(lws + S_W1P);
    const v2f* b1p  = (const v2f*)(lws + S_B1P);
    const v2f* fcwp = (const v2f*)(lws + S_FCWP);

    const int t = blockIdx.x * BLOCK + tid;
    const float* xs = xg + (long long)t * 81;

    const u32x4* bfrag_g = (const u32x4*)wsf;   // [pi*3+kb][lane] x 16B

    f32x16 acc0{};                  // M-tile 0: samples 0..31 (wave-local)
    f32x16 acc1{};                  // M-tile 1: samples 32..63

    const bool h0 = (lane < 32);

    float xb[4][8], xbn[4][8];
    LOADB(xbn, 0);                  // prime the pipeline

    #pragma unroll 1                // rolled: body fits I$
    for (int pi = 0; pi < 3; ++pi) {
        // ---- consume prefetched band (vmcnt wait lands here) ----
        #pragma unroll
        for (int r = 0; r < 4; ++r)
            #pragma unroll
            for (int c = 0; c < 8; ++c) {
                float v = xbn[r][c];
                asm volatile("" : "+v"(v));      // pin: distinct reg, no remat
                xb[r][c] = v;
            }
        // ---- issue next band's x loads + this band's B-frag loads now;
        //      both stay above the math (latency hidden by conv1) ----
        if (pi < 2) LOADB(xbn, pi + 1);
        u32x4 bfr[3];
        #pragma unroll
        for (int kb = 0; kb < 3; ++kb)
            bfr[kb] = bfrag_g[(pi * 3 + kb) * 64 + lane];
        __builtin_amdgcn_sched_barrier(0);

        // ---- conv1 + pool + sigmoid -> packed bf16 pairs pk[24] ----
        u32 pk[24];
        #pragma unroll
        for (int op = 0; op < 8; ++op) {        // channel pair (2op, 2op+1)
            v2f wv[9];
            #pragma unroll
            for (int k = 0; k < 9; ++k) wv[k] = w1p[op * 9 + k];
            const v2f bb = b1p[op];
            v2f vm[3];
            #pragma unroll
            for (int pj = 0; pj < 3; ++pj) {
                v2f vmax;
                #pragma unroll
                for (int dh = 0; dh < 2; ++dh)
                    #pragma unroll
                    for (int dw = 0; dw < 2; ++dw) {
                        v2f s = bb;
                        #pragma unroll
                        for (int i = 0; i < 3; ++i)
                            #pragma unroll
                            for (int jj = 0; jj < 3; ++jj) {
                                float xv = xb[dh + i][2 * pj + dw + jj];
                                s = __builtin_elementwise_fma(
                                        (v2f){xv, xv}, wv[i * 3 + jj], s);
                            }
                        if (dh == 0 && dw == 0) vmax = s;
                        else vmax = __builtin_elementwise_max(vmax, s);
                    }
                vm[pj] = vmax;
            }
            // features f = ch*3+pj, ch = 2op / 2op+1 -> dwords 3op..3op+2
            float s00 = sig2(vm[0].x), s01 = sig2(vm[1].x), s02 = sig2(vm[2].x);
            float s10 = sig2(vm[0].y), s11 = sig2(vm[1].y), s12 = sig2(vm[2].y);
            pk[3 * op + 0] = pack_bf(s00, s01);
            pk[3 * op + 1] = pack_bf(s02, s10);
            pk[3 * op + 2] = pack_bf(s11, s12);
        }

        // ---- A-fragments via half-swap shuffles, then 3 kb of MFMA ----
        #pragma unroll
        for (int kb = 0; kb < 3; ++kb) {
            u32 a0d[4], a1d[4];
            #pragma unroll
            for (int i = 0; i < 4; ++i) {
                u32 lo = pk[kb * 8 + i];         // k = kb*16 + 2i, 2i+1
                u32 hi = pk[kb * 8 + 4 + i];     // k = kb*16 + 8 + 2i, ...
                u32 s  = h0 ? hi : lo;           // what the other half wants
                u32 tt = (u32)__shfl_xor((int)s, 32);
                a0d[i] = h0 ? lo : tt;           // row = lane&31
                a1d[i] = h0 ? tt : hi;           // row = (lane&31)+32
            }
            u32x4 aw0; aw0.x = a0d[0]; aw0.y = a0d[1]; aw0.z = a0d[2]; aw0.w = a0d[3];
            u32x4 aw1; aw1.x = a1d[0]; aw1.y = a1d[1]; aw1.z = a1d[2]; aw1.w = a1d[3];
            bf16x8 bf = __builtin_bit_cast(bf16x8, bfr[kb]);
            acc0 = __builtin_amdgcn_mfma_f32_32x32x16_bf16(
                       __builtin_bit_cast(bf16x8, aw0), bf, acc0, 0, 0, 0);
            acc1 = __builtin_amdgcn_mfma_f32_32x32x16_bf16(
                       __builtin_bit_cast(bf16x8, aw1), bf, acc1, 0, 0, 0);
        }
    }

    // ---- bias + sigmoid on C-layout regs, transpose via LDS ----
    // C/D: col(oc) = lane&31, row = (reg&3) + 8*(reg>>2) + 4*(lane>>5)
    const float b2v = lws[S_B2S + (lane & 31)];
    #pragma unroll
    for (int r = 0; r < 16; ++r) {
        const int srow = (r & 3) + 8 * (r >> 2) + 4 * (lane >> 5);
        scr[srow * 34 + (lane & 31)] =
            __builtin_bit_cast(u32, sig2(acc0[r] + b2v));
        scr[(srow + 32) * 34 + (lane & 31)] =
            __builtin_bit_cast(u32, sig2(acc1[r] + b2v));
    }

    // ---- per-thread fc 32->4 (packed), coalesced float4 store ----
    v2f h2[16];
    #pragma unroll
    for (int j = 0; j < 16; ++j)
        h2[j] = *(const v2f*)((const float*)scr + lane * 34 + 2 * j);

    v2f a0 = h2[0] * fcwp[0],  a1 = h2[0] * fcwp[16],
        a2 = h2[0] * fcwp[32], a3 = h2[0] * fcwp[48];
    #pragma unroll
    for (int j = 1; j < 16; ++j) {
        a0 = __builtin_elementwise_fma(h2[j], fcwp[0 * 16 + j], a0);
        a1 = __builtin_elementwise_fma(h2[j], fcwp[1 * 16 + j], a1);
        a2 = __builtin_elementwise_fma(h2[j], fcwp[2 * 16 + j], a2);
        a3 = __builtin_elementwise_fma(h2[j], fcwp[3 * 16 + j], a3);
    }
    ((float4*)out)[t] = make_float4(fcb[0] + a0.x + a0.y,
                                    fcb[1] + a1.x + a1.y,
                                    fcb[2] + a2.x + a2.y,
                                    fcb[3] + a3.x + a3.y);
}

extern "C" void kernel_launch(void* const* d_in, const int* in_sizes, int n_in,
                              void* d_out, int out_size, void* d_ws, size_t ws_size,
                              hipStream_t stream) {
    const float* x   = (const float*)d_in[0];
    const float* w1  = (const float*)d_in[1];
    const float* b1  = (const float*)d_in[2];
    const float* w2  = (const float*)d_in[3];
    const float* b2  = (const float*)d_in[4];
    const float* fcw = (const float*)d_in[5];
    const float* fcb = (const float*)d_in[6];
    float* out = (float*)d_out;
    float* ws  = (float*)d_ws;        // ~10.5 KB used

    prep_kernel<<<dim3((PREP_ITEMS + 255) / 256), dim3(256), 0, stream>>>(
        w1, b1, w2, b2, fcw, ws);

    const int nB = in_sizes[0] / 81;  // 131072, divisible by BLOCK
    olcnn_kernel<<<dim3(nB / BLOCK), dim3(BLOCK), 0, stream>>>(x, ws, fcb, out);
}